// Round 1
// baseline (363.788 us; speedup 1.0000x reference)
//
#include <hip/hip_runtime.h>
#include <stdint.h>

#define CIN 128
#define COUT 256
#define NIN 400000
#define MOUT 100000
#define KOFFS 8
#define EPSV 1e-4f
#define BM 64

typedef __attribute__((ext_vector_type(8))) short short8;
typedef __attribute__((ext_vector_type(4))) float f32x4;

__device__ __forceinline__ unsigned f2bf_u(float f) {
    union { float f; unsigned u; } v; v.f = f;
    return (v.u + 0x7FFFu + ((v.u >> 16) & 1u)) >> 16;  // RNE bf16
}

// ---------------------------------------------------------------------------
// Kernel 0: transpose W[k][c][n] (fp32) -> Wt[k][n][c] (bf16) + zero BN stats
// ---------------------------------------------------------------------------
__global__ void prep_kernel(const float* __restrict__ W,
                            unsigned short* __restrict__ Wt,
                            float* __restrict__ gstat) {
    __shared__ unsigned short t[CIN][COUT + 2];  // +2 pad: conflict-free col reads
    const int k = blockIdx.x;
    const int tid = threadIdx.x;  // 256 threads
    if (k == 0) { gstat[tid] = 0.f; gstat[tid + 256] = 0.f; }
    const float* Wk = W + k * (CIN * COUT);
    for (int c = 0; c < CIN; ++c)
        t[c][tid] = (unsigned short)f2bf_u(Wk[c * COUT + tid]);  // coalesced
    __syncthreads();
    unsigned short* Wtk = Wt + k * (CIN * COUT);
    for (int i = 0; i < CIN; ++i) {
        int j = i * 256 + tid;       // flat dst index = n*128 + c
        int n = j >> 7, c = j & 127;
        Wtk[j] = t[c][n];            // coalesced 2B writes
    }
}

// ---------------------------------------------------------------------------
// Kernel 1: gather-GEMM conv (bf16 MFMA) + per-channel sum/sumsq atomics
// ---------------------------------------------------------------------------
__global__ __launch_bounds__(256) void conv_kernel(
    const float* __restrict__ feats,
    const unsigned short* __restrict__ Wt,
    const int* __restrict__ gidx,
    float* __restrict__ out,
    float* __restrict__ gstat) {
  // XOR-swizzled tiles: byte ^= (row&7)<<4  (fixes 16-way conflict at 256B row stride)
  __shared__ unsigned short Abuf[BM * CIN];    // 16 KB
  __shared__ unsigned short Bbuf[COUT * CIN];  // 64 KB
  __shared__ int IDX[BM * KOFFS];              // 2 KB

  const int tid = threadIdx.x;
  const int lane = tid & 63;
  const int wave = tid >> 6;          // 4 waves, each owns 64 output cols
  const long base_m = (long)blockIdx.x * BM;

  for (int i = tid; i < BM * KOFFS; i += 256) {
    long g = base_m * KOFFS + i;
    IDX[i] = (g < (long)MOUT * KOFFS) ? gidx[g] : NIN;  // tail rows -> inactive
  }
  __syncthreads();

  f32x4 acc[4][4];
  #pragma unroll
  for (int mi = 0; mi < 4; ++mi)
    #pragma unroll
    for (int ni = 0; ni < 4; ++ni)
      acc[mi][ni] = (f32x4){0.f, 0.f, 0.f, 0.f};

  const int row16 = lane & 15;  // frag row (A) / col (B,D)
  const int quad = lane >> 4;   // k-chunk group
  const int arow = tid >> 5;    // A staging: 8 rows per pass, 32 lanes/row
  const int achunk = tid & 31;

  for (int k = 0; k < KOFFS; ++k) {
    // ---- stage B: Wt[k] is already [n][c] bf16; straight 64KB copy, swizzled
    const unsigned short* Wk = Wt + k * (CIN * COUT);
    #pragma unroll
    for (int p = 0; p < 16; ++p) {
      int u = p * 256 + tid;                       // 16B unit index
      int n = u >> 4;
      int dst = ((n << 8) + ((u & 15) << 4)) ^ ((n & 7) << 4);
      *(uint4*)((char*)Bbuf + dst) = *(const uint4*)((const char*)Wk + (u << 4));
    }
    // ---- stage A: gather 64 feats rows (512B fully coalesced per 32 lanes)
    #pragma unroll
    for (int p = 0; p < 8; ++p) {
      int r = p * 8 + arow;
      int idx = IDX[r * KOFFS + k];
      float4 v = make_float4(0.f, 0.f, 0.f, 0.f);
      if (idx < NIN)
        v = *(const float4*)(feats + (long)idx * CIN + (achunk << 2));
      uint2 pk;
      pk.x = f2bf_u(v.x) | (f2bf_u(v.y) << 16);
      pk.y = f2bf_u(v.z) | (f2bf_u(v.w) << 16);
      int dst = ((r << 8) + (achunk << 3)) ^ ((r & 7) << 4);
      *(uint2*)((char*)Abuf + dst) = pk;
    }
    __syncthreads();
    // ---- MFMA: K=128 per offset = 4 k-steps of 32
    #pragma unroll
    for (int ks = 0; ks < 4; ++ks) {
      short8 af[4], bfr[4];
      #pragma unroll
      for (int mi = 0; mi < 4; ++mi) {
        int r = mi * 16 + row16;
        int off = ((r << 8) + (ks << 6) + (quad << 4)) ^ ((r & 7) << 4);
        af[mi] = *(const short8*)((const char*)Abuf + off);
      }
      #pragma unroll
      for (int ni = 0; ni < 4; ++ni) {
        int n = (wave << 6) + ni * 16 + row16;
        int off = ((n << 8) + (ks << 6) + (quad << 4)) ^ ((n & 7) << 4);
        bfr[ni] = *(const short8*)((const char*)Bbuf + off);
      }
      #pragma unroll
      for (int mi = 0; mi < 4; ++mi)
        #pragma unroll
        for (int ni = 0; ni < 4; ++ni)
          acc[mi][ni] = __builtin_amdgcn_mfma_f32_16x16x32_bf16(
              af[mi], bfr[ni], acc[mi][ni], 0, 0, 0);
    }
    __syncthreads();
  }

  // ---- epilogue: raw conv out + per-channel stats
  // C/D layout: col = lane&15, row = quad*4 + reg   [m89-verified]
  float s[4], sq[4];
  #pragma unroll
  for (int ni = 0; ni < 4; ++ni) { s[ni] = 0.f; sq[ni] = 0.f; }
  #pragma unroll
  for (int mi = 0; mi < 4; ++mi) {
    #pragma unroll
    for (int rr = 0; rr < 4; ++rr) {
      long m = base_m + mi * 16 + quad * 4 + rr;
      bool ok = (m < MOUT);
      #pragma unroll
      for (int ni = 0; ni < 4; ++ni) {
        float v = acc[mi][ni][rr];
        if (ok) out[m * COUT + (wave << 6) + ni * 16 + row16] = v;
        s[ni] += v;            // tail rows are exact zeros -> stats unaffected
        sq[ni] += v * v;
      }
    }
  }
  #pragma unroll
  for (int ni = 0; ni < 4; ++ni) {
    s[ni] += __shfl_xor(s[ni], 16);
    s[ni] += __shfl_xor(s[ni], 32);
    sq[ni] += __shfl_xor(sq[ni], 16);
    sq[ni] += __shfl_xor(sq[ni], 32);
  }
  if (quad == 0) {
    #pragma unroll
    for (int ni = 0; ni < 4; ++ni) {
      int n = (wave << 6) + ni * 16 + row16;
      atomicAdd(&gstat[n], s[ni]);
      atomicAdd(&gstat[n + 256], sq[ni]);
    }
  }
}

// ---------------------------------------------------------------------------
// Kernel 2: stats -> scale/shift
// ---------------------------------------------------------------------------
__global__ void finalize_kernel(const float* __restrict__ gstat,
                                const float* __restrict__ gamma,
                                const float* __restrict__ beta,
                                float* __restrict__ ss) {
  int n = threadIdx.x;
  const float inv = 1.0f / (float)MOUT;
  float mu = gstat[n] * inv;
  float var = gstat[n + 256] * inv - mu * mu;
  float sc = rsqrtf(var + EPSV) * gamma[n];
  ss[n] = sc;
  ss[n + 256] = beta[n] - mu * sc;
}

// ---------------------------------------------------------------------------
// Kernel 3: in-place BN + ReLU on d_out
// ---------------------------------------------------------------------------
__global__ void apply_kernel(float* __restrict__ out, const float* __restrict__ ss) {
  __shared__ float sc[256], sh[256];
  sc[threadIdx.x] = ss[threadIdx.x];
  sh[threadIdx.x] = ss[threadIdx.x + 256];
  __syncthreads();
  const long total = (long)MOUT * COUT / 4;
  float4* o4 = (float4*)out;
  for (long i = (long)blockIdx.x * blockDim.x + threadIdx.x; i < total;
       i += (long)gridDim.x * blockDim.x) {
    float4 v = o4[i];
    int c = (int)(i & 63) << 2;
    v.x = fmaxf(fmaf(v.x, sc[c],     sh[c]),     0.f);
    v.y = fmaxf(fmaf(v.y, sc[c + 1], sh[c + 1]), 0.f);
    v.z = fmaxf(fmaf(v.z, sc[c + 2], sh[c + 2]), 0.f);
    v.w = fmaxf(fmaf(v.w, sc[c + 3], sh[c + 3]), 0.f);
    o4[i] = v;
  }
}

// ---------------------------------------------------------------------------
extern "C" void kernel_launch(void* const* d_in, const int* in_sizes, int n_in,
                              void* d_out, int out_size, void* d_ws, size_t ws_size,
                              hipStream_t stream) {
  const float* feats = (const float*)d_in[0];
  const float* W     = (const float*)d_in[1];
  const float* gamma = (const float*)d_in[2];
  const float* beta  = (const float*)d_in[3];
  const int*   gidx  = (const int*)d_in[4];
  float* out = (float*)d_out;

  float* gstat = (float*)d_ws;                              // 512 f32: sum, sumsq
  float* ss    = (float*)((char*)d_ws + 2048);              // 512 f32: scale, shift
  unsigned short* Wt = (unsigned short*)((char*)d_ws + 4096); // 8*256*128 bf16 = 512KB

  hipLaunchKernelGGL(prep_kernel, dim3(KOFFS), dim3(256), 0, stream, W, Wt, gstat);
  hipLaunchKernelGGL(conv_kernel, dim3((MOUT + BM - 1) / BM), dim3(256), 0, stream,
                     feats, Wt, gidx, out, gstat);
  hipLaunchKernelGGL(finalize_kernel, dim3(1), dim3(256), 0, stream,
                     gstat, gamma, beta, ss);
  hipLaunchKernelGGL(apply_kernel, dim3(2048), dim3(256), 0, stream, out, ss);
}

// Round 2
// 182.133 us; speedup vs baseline: 1.9974x; 1.9974x over previous
//
#include <hip/hip_runtime.h>
#include <stdint.h>

#define CIN 128
#define COUT 256
#define NIN 400000
#define MOUT 100000
#define KOFFS 8
#define EPSV 1e-4f
#define BM 256
#define BK 64
#define NT 16        // K-steps: 8 offsets * 128 ch / 64
#define THREADS 512

typedef __attribute__((ext_vector_type(8))) short short8;
typedef __attribute__((ext_vector_type(4))) float f32x4;
typedef __attribute__((address_space(3))) uint32_t lds_u32;
typedef const __attribute__((address_space(1))) uint32_t glb_u32;

__device__ __forceinline__ unsigned f2bf_u(float f) {
  union { float f; unsigned u; } v; v.f = f;
  return (v.u + 0x7FFFu + ((v.u >> 16) & 1u)) >> 16;  // RNE bf16
}

// ---------------------------------------------------------------------------
// Kernel 0: W[k][c][n] fp32 -> Wt_swz: 16 contiguous 32 KB blocks.
// Block s holds the B-tile for K-step s (k_total = s*64..s*64+63) in the
// EXACT (inverse-swizzled) byte order conv wants in LDS:
//   read at byte n*128 + (inner ^ ((n&7)<<4)) yields element (n, c2=inner/2)
// so uint4 slot j of row n holds unswizzled slot j ^ (n&7).
// Also zeroes the BN stat accumulators (d_ws is poisoned by the harness).
// ---------------------------------------------------------------------------
__global__ void prep_kernel(const float* __restrict__ W,
                            unsigned short* __restrict__ Wt,
                            float* __restrict__ gstat) {
  const int s = blockIdx.x;   // 0..15
  const int n = threadIdx.x;  // 0..255
  if (s == 0) { gstat[n] = 0.f; gstat[n + 256] = 0.f; }
  const int koff = s >> 1;
  const int cbase = (s & 1) * 64;
  const float* Wk = W + koff * (CIN * COUT);
  unsigned short row[64];
  #pragma unroll
  for (int c = 0; c < 64; ++c)  // coalesced: lanes n consecutive per c
    row[c] = (unsigned short)f2bf_u(Wk[(cbase + c) * COUT + n]);
  uint4* dst = (uint4*)((char*)Wt + s * 32768 + n * 128);
  #pragma unroll
  for (int j = 0; j < 8; ++j) {
    const unsigned short* p = &row[(j ^ (n & 7)) * 8];
    uint4 v;
    v.x = (unsigned)p[0] | ((unsigned)p[1] << 16);
    v.y = (unsigned)p[2] | ((unsigned)p[3] << 16);
    v.z = (unsigned)p[4] | ((unsigned)p[5] << 16);
    v.w = (unsigned)p[6] | ((unsigned)p[7] << 16);
    dst[j] = v;
  }
}

// ---------------------------------------------------------------------------
// Kernel 1: gather-GEMM conv, 256x256 tile, 8 waves, 2-phase dbuf pipeline.
// ---------------------------------------------------------------------------
__global__ __launch_bounds__(THREADS, 2) void conv_kernel(
    const float* __restrict__ feats,
    const unsigned short* __restrict__ Wt,
    const int* __restrict__ gidx,
    float* __restrict__ out,
    float* __restrict__ gstat) {
  __shared__ unsigned short Ab[2][BM * BK];    // 2 x 32 KB
  __shared__ unsigned short Bb[2][COUT * BK];  // 2 x 32 KB
  __shared__ int IDX[BM * KOFFS];              // 8 KB

  const int tid = threadIdx.x;
  const int lane = tid & 63;
  const int wave = tid >> 6;   // 0..7
  const int wm = wave >> 2;    // M half (0..1)
  const int wn = wave & 3;     // N quarter (0..3)
  const int row16 = lane & 15;
  const int quad = lane >> 4;
  const long base_m = (long)blockIdx.x * BM;

  for (int i = tid; i < BM * KOFFS; i += THREADS) {
    long m = base_m + (i >> 3);
    IDX[i] = (m < MOUT) ? gidx[m * KOFFS + (i & 7)] : NIN;
  }
  __syncthreads();

  const int ar = tid >> 4;   // A staging: 32 rows/pass, 8 passes
  const int ac = tid & 15;   // 16B chunk within 64-ch slice

  // --- staging helpers ---
  float4 st[8];
  auto A_LOAD = [&](int s) {
    const int koff = s >> 1;
    const int cb = ((s & 1) << 6) + (ac << 2);
    #pragma unroll
    for (int p = 0; p < 8; ++p) {
      int idx = IDX[(p * 32 + ar) * KOFFS + koff];
      st[p] = (idx < NIN) ? *(const float4*)(feats + (long)idx * CIN + cb)
                          : make_float4(0.f, 0.f, 0.f, 0.f);
    }
  };
  auto A_WRITE = [&](int b) {
    #pragma unroll
    for (int p = 0; p < 8; ++p) {
      int r = p * 32 + ar;
      uint2 pk;
      pk.x = f2bf_u(st[p].x) | (f2bf_u(st[p].y) << 16);
      pk.y = f2bf_u(st[p].z) | (f2bf_u(st[p].w) << 16);
      *(uint2*)((char*)Ab[b] + r * 128 + ((ac << 3) ^ ((r & 7) << 4))) = pk;
    }
  };
  auto B_STAGE = [&](int s, int b) {
    const char* src = (const char*)Wt + s * 32768 + (wave << 12) + (lane << 4);
    char* dstb = (char*)Bb[b] + (wave << 12) + (lane << 4);
    #pragma unroll
    for (int i = 0; i < 4; ++i)
      __builtin_amdgcn_global_load_lds((glb_u32*)(src + i * 1024),
                                       (lds_u32*)(dstb + i * 1024), 16, 0, 0);
  };

  f32x4 acc[8][4];
  #pragma unroll
  for (int mi = 0; mi < 8; ++mi)
    #pragma unroll
    for (int ni = 0; ni < 4; ++ni)
      acc[mi][ni] = (f32x4){0.f, 0.f, 0.f, 0.f};

  auto MMA = [&](int b) {
    #pragma unroll
    for (int ks = 0; ks < 2; ++ks) {
      short8 af[8], bfr[4];
      const int inner = (ks << 6) + (quad << 4);
      #pragma unroll
      for (int mi = 0; mi < 8; ++mi) {
        int r = (wm << 7) + (mi << 4) + row16;
        af[mi] = *(const short8*)((const char*)Ab[b] + r * 128 +
                                  (inner ^ ((r & 7) << 4)));
      }
      #pragma unroll
      for (int ni = 0; ni < 4; ++ni) {
        int n = (wn << 6) + (ni << 4) + row16;
        bfr[ni] = *(const short8*)((const char*)Bb[b] + n * 128 +
                                   (inner ^ ((n & 7) << 4)));
      }
      #pragma unroll
      for (int mi = 0; mi < 8; ++mi)
        #pragma unroll
        for (int ni = 0; ni < 4; ++ni)
          acc[mi][ni] = __builtin_amdgcn_mfma_f32_16x16x32_bf16(
              af[mi], bfr[ni], acc[mi][ni], 0, 0, 0);
    }
  };

  // --- prologue ---
  A_LOAD(0);
  B_STAGE(0, 0);
  A_WRITE(0);
  __syncthreads();

  // --- 2-phase main loop: STAGE(next) overlaps MFMA(cur) ---
  int cb = 0;
  for (int s = 0; s < NT - 1; ++s) {
    A_LOAD(s + 1);          // issue gathers early (T14)
    B_STAGE(s + 1, cb ^ 1); // async global->LDS, in flight across MFMA
    MMA(cb);
    A_WRITE(cb ^ 1);        // vmcnt wait lands here, latency already hidden
    __syncthreads();
    cb ^= 1;
  }
  MMA(cb);

  // --- epilogue: store conv out + per-channel sum/sumsq ---
  // C/D layout: col = lane&15, row = quad*4 + rr  [m89-verified]
  float sm[4], sq[4];
  #pragma unroll
  for (int ni = 0; ni < 4; ++ni) { sm[ni] = 0.f; sq[ni] = 0.f; }
  #pragma unroll
  for (int mi = 0; mi < 8; ++mi) {
    #pragma unroll
    for (int rr = 0; rr < 4; ++rr) {
      long m = base_m + (wm << 7) + (mi << 4) + (quad << 2) + rr;
      bool ok = (m < MOUT);
      #pragma unroll
      for (int ni = 0; ni < 4; ++ni) {
        float v = acc[mi][ni][rr];
        if (ok) out[m * COUT + (wn << 6) + (ni << 4) + row16] = v;
        sm[ni] += v;   // tail rows gather the zero pad -> exact zeros
        sq[ni] += v * v;
      }
    }
  }
  #pragma unroll
  for (int ni = 0; ni < 4; ++ni) {
    sm[ni] += __shfl_xor(sm[ni], 16);
    sm[ni] += __shfl_xor(sm[ni], 32);
    sq[ni] += __shfl_xor(sq[ni], 16);
    sq[ni] += __shfl_xor(sq[ni], 32);
  }
  if (quad == 0) {
    #pragma unroll
    for (int ni = 0; ni < 4; ++ni) {
      int n = (wn << 6) + (ni << 4) + row16;
      atomicAdd(&gstat[n], sm[ni]);
      atomicAdd(&gstat[n + 256], sq[ni]);
    }
  }
}

// ---------------------------------------------------------------------------
// Kernel 2: stats -> scale/shift
// ---------------------------------------------------------------------------
__global__ void finalize_kernel(const float* __restrict__ gstat,
                                const float* __restrict__ gamma,
                                const float* __restrict__ beta,
                                float* __restrict__ ss) {
  int n = threadIdx.x;
  const float inv = 1.0f / (float)MOUT;
  float mu = gstat[n] * inv;
  float var = gstat[n + 256] * inv - mu * mu;
  float sc = rsqrtf(var + EPSV) * gamma[n];
  ss[n] = sc;
  ss[n + 256] = beta[n] - mu * sc;
}

// ---------------------------------------------------------------------------
// Kernel 3: in-place BN + ReLU on d_out
// ---------------------------------------------------------------------------
__global__ void apply_kernel(float* __restrict__ out, const float* __restrict__ ss) {
  __shared__ float sc[256], sh[256];
  sc[threadIdx.x] = ss[threadIdx.x];
  sh[threadIdx.x] = ss[threadIdx.x + 256];
  __syncthreads();
  const long total = (long)MOUT * COUT / 4;
  float4* o4 = (float4*)out;
  for (long i = (long)blockIdx.x * blockDim.x + threadIdx.x; i < total;
       i += (long)gridDim.x * blockDim.x) {
    float4 v = o4[i];
    int c = (int)(i & 63) << 2;
    v.x = fmaxf(fmaf(v.x, sc[c],     sh[c]),     0.f);
    v.y = fmaxf(fmaf(v.y, sc[c + 1], sh[c + 1]), 0.f);
    v.z = fmaxf(fmaf(v.z, sc[c + 2], sh[c + 2]), 0.f);
    v.w = fmaxf(fmaf(v.w, sc[c + 3], sh[c + 3]), 0.f);
    o4[i] = v;
  }
}

// ---------------------------------------------------------------------------
extern "C" void kernel_launch(void* const* d_in, const int* in_sizes, int n_in,
                              void* d_out, int out_size, void* d_ws, size_t ws_size,
                              hipStream_t stream) {
  const float* feats = (const float*)d_in[0];
  const float* W     = (const float*)d_in[1];
  const float* gamma = (const float*)d_in[2];
  const float* beta  = (const float*)d_in[3];
  const int*   gidx  = (const int*)d_in[4];
  float* out = (float*)d_out;

  float* gstat = (float*)d_ws;                                // 512 f32
  float* ss    = (float*)((char*)d_ws + 2048);                // 512 f32
  unsigned short* Wt = (unsigned short*)((char*)d_ws + 4096); // 512 KB pre-swizzled

  hipLaunchKernelGGL(prep_kernel, dim3(NT), dim3(256), 0, stream, W, Wt, gstat);
  hipLaunchKernelGGL(conv_kernel, dim3((MOUT + BM - 1) / BM), dim3(THREADS), 0,
                     stream, feats, Wt, gidx, out, gstat);
  hipLaunchKernelGGL(finalize_kernel, dim3(1), dim3(256), 0, stream,
                     gstat, gamma, beta, ss);
  hipLaunchKernelGGL(apply_kernel, dim3(2048), dim3(256), 0, stream, out, ss);
}